// Round 8
// baseline (376.708 us; speedup 1.0000x reference)
//
#include <hip/hip_runtime.h>
#include <hip/hip_bf16.h>
#include <math.h>

#define GG 8192      // graphs = B*T
#define NODESN 23
#define KK 8
#define DIN 16
#define HH 128
#define RHH 128
#define EPG (NODESN*KK)   // 184 edges per graph
#define TTT 128
#define BBB 64

// ---------------------------------------------------------------------------
// DPP cross-lane add (VALU pipe -- NOT the DS pipe, unlike __shfl_xor).
// ---------------------------------------------------------------------------
template<int CTRL>
static __device__ __forceinline__ float dpp_add(float v) {
    int x = __builtin_amdgcn_update_dpp(0, __float_as_int(v), CTRL, 0xF, 0xF, true);
    return v + __int_as_float(x);
}
#define DPP_XOR1 0xB1   // quad_perm [1,0,3,2]
#define DPP_XOR2 0x4E   // quad_perm [2,3,0,1]
#define DPP_MIR7 0x141  // row_half_mirror: lane l <-> l^7 within 8-lane half-row
#define DPP_SHL4 0x104  // row_shl:4 (lane l <- lane l+4)

#define PIN4(v4) asm volatile("" : "+v"((v4).x), "+v"((v4).y), "+v"((v4).z), "+v"((v4).w))

// ---------------------------------------------------------------------------
// Kernel 1 (R15): the ENTIRE front-end in one kernel.
//   phase 1: t1 = x @ W1 (x rows scalarized via readfirstlane half-index)
//   phase 2: runner-neighborhood aggregation -> hs (GCN-1 + relu + sum)
//   phase 3: srow = relu((hs @ W2)/9 + b2)  (kept in LDS, never hits HBM)
//   phase 4: xg[g][jj] = dot(srow, W_ih[jj]) + b_ih[jj]  (W_ih read
//            row-major directly -> transpose kernel deleted; xg_kernel
//            deleted; seq/WT workspace buffers deleted)
// 256 threads, ~14 KB LDS -> occupancy stays wave-slot-limited at 8
// blocks/CU, identical to the R14 split version (R10 lesson: never trade
// occupancy for fusion).  Launch count: 4 -> 2.
// Phase-4 jj mapping: jj = tid, and jj = tid+256 for tid<128 -> trip count
// is wave-uniform (waves 0-1: 2 iters, waves 2-3: 1), xg writes coalesced,
// srow reads are same-address LDS broadcasts (conflict-free).
// ---------------------------------------------------------------------------
__global__ __launch_bounds__(256) void gcn_front(
    const float* __restrict__ x, const int* __restrict__ esrc,
    const int* __restrict__ runner,
    const float* __restrict__ W1, const float* __restrict__ b1,
    const float* __restrict__ W2, const float* __restrict__ b2,
    const float* __restrict__ W_ih, const float* __restrict__ b_ih,
    float* __restrict__ xg)
{
    __shared__ float t1[NODESN * HH];   // 11776 B
    __shared__ float red[256];          //  1024 B
    __shared__ float hs[HH];            //   512 B
    __shared__ float srow[HH];          //   512 B

    const int g   = blockIdx.x;
    const int tid = threadIdx.x;
    const int j   = tid & 127;
    // wave-uniform half index, provably uniform -> downstream uniform-address
    // loads scalarize to s_load.
    const int nhu = __builtin_amdgcn_readfirstlane(tid >> 7);

    // ---- W1 column j -> registers
    float w[DIN];
    #pragma unroll
    for (int k = 0; k < DIN; k++) w[k] = W1[k * HH + j];
    const float b1j = b1[j];

    // ---- phase 1: t1 = x @ W1 (pre-bias); x rows read scalar (uniform addr)
    const float* xgp = x + (size_t)g * NODESN * DIN;
    const int n0 = nhu ? 12 : 0;
    const int n1 = nhu ? NODESN : 12;
    for (int n = n0; n < n1; n++) {
        const float4* xr = (const float4*)(xgp + n * DIN);
        float4 a0 = xr[0], a1 = xr[1], a2 = xr[2], a3 = xr[3];
        float acc;
        acc = fmaf(a0.x, w[0],  fmaf(a0.y, w[1],  fmaf(a0.z, w[2],  fmaf(a0.w, w[3],
              fmaf(a1.x, w[4],  fmaf(a1.y, w[5],  fmaf(a1.z, w[6],  fmaf(a1.w, w[7],
              fmaf(a2.x, w[8],  fmaf(a2.y, w[9],  fmaf(a2.z, w[10], fmaf(a2.w, w[11],
              fmaf(a3.x, w[12], fmaf(a3.y, w[13], fmaf(a3.z, w[14], fmaf(a3.w, w[15],
              0.f))))))))))))))));
        t1[n * HH + j] = acc;
    }
    __syncthreads();

    // ---- phase 2: runner-neighborhood aggregation (edge indices scalar)
    const int* eg = esrc + (size_t)g * EPG;
    const int gb = g * NODESN;
    const int r  = runner[g];
    float part = 0.f;
    for (int slot = nhu; slot < 9; slot += 2) {
        int node = (slot < 8) ? (eg[r * KK + slot] - gb) : r;
        float acc = t1[node * HH + j];
        #pragma unroll
        for (int k = 0; k < KK; k++) acc += t1[(eg[node * KK + k] - gb) * HH + j];
        part += fmaxf(acc * (1.f / 9.f) + b1j, 0.f);
    }
    red[tid] = part;
    __syncthreads();
    if (tid < HH) hs[tid] = red[tid] + red[tid + 128];
    __syncthreads();

    // ---- phase 3: srow = relu((hs @ W2) / 9 + b2)  (LDS only)
    {
        const int k0 = nhu * 64;
        float acc = 0.f;
        #pragma unroll 4
        for (int kk = 0; kk < 64; kk += 4) {
            int k = k0 + kk;
            float4 hv = *(const float4*)&hs[k];
            acc = fmaf(hv.x, W2[(k + 0) * HH + j],
                  fmaf(hv.y, W2[(k + 1) * HH + j],
                  fmaf(hv.z, W2[(k + 2) * HH + j],
                  fmaf(hv.w, W2[(k + 3) * HH + j], acc))));
        }
        red[tid] = acc;
        __syncthreads();
        if (tid < HH)
            srow[tid] = fmaxf((red[tid] + red[tid + 128]) * (1.f / 9.f) + b2[tid], 0.f);
        __syncthreads();
    }

    // ---- phase 4: xg row = srow @ W_ih^T + b_ih (W_ih row-major direct)
    float* xrow = xg + (size_t)g * 3 * RHH;
    for (int jj = tid; jj < 3 * RHH; jj += 256) {
        const float* wrow = W_ih + (size_t)jj * RHH;
        float acc = b_ih[jj];
        #pragma unroll 4
        for (int k = 0; k < RHH; k += 4) {
            float4 wv = *(const float4*)(wrow + k);
            float4 hv = *(const float4*)&srow[k];
            acc = fmaf(hv.x, wv.x, fmaf(hv.y, wv.y, fmaf(hv.z, wv.z, fmaf(hv.w, wv.w, acc))));
        }
        xrow[jj] = acc;
    }
}

// ---------------------------------------------------------------------------
// Kernel 5: GRU (byte-identical to R13/R14: 512 thr, ~99 us -- control).
// ---------------------------------------------------------------------------
#define CHUNK 32
#define XGB_FLOATS (CHUNK * HH * 4)      // 16384 floats = 64 KB

__global__ __launch_bounds__(512)
__attribute__((amdgpu_waves_per_eu(2, 2)))
void gru_kernel(
    const float* __restrict__ xg, const float* __restrict__ W_hh,
    const float* __restrict__ b_hh, const float* __restrict__ Wp,
    const float* __restrict__ bp, float* __restrict__ out)
{
    __shared__ float xgbuf[XGB_FLOATS];          // [tl][i][{xr,xz,xn,pad}]
    __shared__ float houtb[(CHUNK + 2) * HH];    // rows 1..32 = h(t); row 32 also carry
    __shared__ float wps[2 * RHH + 2];           // Wp + bp

    const int b   = blockIdx.x;
    const int tid = threadIdx.x;
    const int kq  = tid & 7;       // k-eighth, lane bits 0-2 (DPP butterfly domain)
    const int i0  = tid >> 3;      // unit pair 0..63
    const int uhf = kq >> 2;       // which unit of the pair this lane's gates handle
    const int u   = 2 * i0 + uhf;  // this lane's gate unit

    float4 wr0[4], wz0[4], wn0[4], wr1[4], wz1[4], wn1[4];
    int hof[4];
    {
        const float* w0 = W_hh + (size_t)(2 * i0) * RHH + kq * 16;
        #pragma unroll
        for (int m = 0; m < 4; m++) {
            const int off = 4 * ((m + kq) & 3);
            hof[m] = kq * 16 + off;
            wr0[m] = *(const float4*)(w0 + off);
            wz0[m] = *(const float4*)(w0 + RHH * RHH + off);
            wn0[m] = *(const float4*)(w0 + 2 * RHH * RHH + off);
            wr1[m] = *(const float4*)(w0 + RHH + off);
            wz1[m] = *(const float4*)(w0 + RHH * RHH + RHH + off);
            wn1[m] = *(const float4*)(w0 + 2 * RHH * RHH + RHH + off);
        }
    }
    #pragma unroll
    for (int m = 0; m < 4; m++) {
        PIN4(wr0[m]); PIN4(wz0[m]); PIN4(wn0[m]);
        PIN4(wr1[m]); PIN4(wz1[m]); PIN4(wn1[m]);
    }
    const float bhr = b_hh[u];
    const float bhz = b_hh[RHH + u];
    const float bhn = b_hh[2 * RHH + u];

    if (tid < 2 * RHH) wps[tid] = Wp[tid];
    if (tid < 2)       wps[2 * RHH + tid] = bp[tid];
    if (tid < HH)      houtb[CHUNK * HH + tid] = 0.f;   // carry row = h(-1) = 0
    float hprev = 0.f;

    const float* xbase = xg + (size_t)b * TTT * 3 * RHH;
    float* outb = out + (size_t)b * TTT * 2;

    for (int c = 0; c < TTT / CHUNK; c++) {
        #pragma unroll
        for (int k2 = 0; k2 < 8; k2++) {
            int slot = tid + (k2 << 9);          // 0..4095
            int tl = slot >> 7, ii = slot & 127;
            const float* gsrc = xbase + (size_t)(c * CHUNK + tl) * 384 + ii;
            float4 v;
            v.x = gsrc[0]; v.y = gsrc[128]; v.z = gsrc[256]; v.w = 0.f;
            *(float4*)&xgbuf[slot << 2] = v;
        }
        if (c > 0) {
            const int s  = tid & 7;              // 16-float k-slice
            const int cc = (tid >> 3) & 1;
            const int tl = tid >> 4;             // 0..31
            const float* hr = &houtb[(tl + 1) * HH + s * 16];
            float acc = 0.f;
            #pragma unroll
            for (int m = 0; m < 16; m += 4) {
                float4 hv = *(const float4*)(hr + m);
                int k = s * 16 + m;
                acc = fmaf(hv.x, wps[(k+0)*2 + cc],
                      fmaf(hv.y, wps[(k+1)*2 + cc],
                      fmaf(hv.z, wps[(k+2)*2 + cc],
                      fmaf(hv.w, wps[(k+3)*2 + cc], acc))));
            }
            acc = dpp_add<DPP_XOR1>(acc);
            acc = dpp_add<DPP_XOR2>(acc);
            acc = dpp_add<DPP_SHL4>(acc);        // valid in lanes s<4
            if (s == 0)
                outb[((c - 1) * CHUNK + tl) * 2 + cc] = acc + wps[2 * RHH + cc];
        }
        __syncthreads();

        float4 xgv = *(const float4*)&xgbuf[u << 2];   // tl=0 row
        for (int tl = 0; tl < CHUNK; tl++) {
            const float* hrow = &houtb[(tl == 0 ? CHUNK : tl) * HH];
            float4 xgn = xgv;
            if (tl + 1 < CHUNK)
                xgn = *(const float4*)&xgbuf[((tl + 1) * HH + u) << 2];

            float ar0 = 0.f, az0 = 0.f, an0 = 0.f;
            float ar1 = 0.f, az1 = 0.f, an1 = 0.f;
            #pragma unroll
            for (int m = 0; m < 4; m++) {
                float4 hv = *(const float4*)(hrow + hof[m]);
                ar0 = fmaf(hv.x, wr0[m].x, fmaf(hv.y, wr0[m].y, fmaf(hv.z, wr0[m].z, fmaf(hv.w, wr0[m].w, ar0))));
                az0 = fmaf(hv.x, wz0[m].x, fmaf(hv.y, wz0[m].y, fmaf(hv.z, wz0[m].z, fmaf(hv.w, wz0[m].w, az0))));
                an0 = fmaf(hv.x, wn0[m].x, fmaf(hv.y, wn0[m].y, fmaf(hv.z, wn0[m].z, fmaf(hv.w, wn0[m].w, an0))));
                ar1 = fmaf(hv.x, wr1[m].x, fmaf(hv.y, wr1[m].y, fmaf(hv.z, wr1[m].z, fmaf(hv.w, wr1[m].w, ar1))));
                az1 = fmaf(hv.x, wz1[m].x, fmaf(hv.y, wz1[m].y, fmaf(hv.z, wz1[m].z, fmaf(hv.w, wz1[m].w, az1))));
                an1 = fmaf(hv.x, wn1[m].x, fmaf(hv.y, wn1[m].y, fmaf(hv.z, wn1[m].z, fmaf(hv.w, wn1[m].w, an1))));
            }
            ar0 = dpp_add<DPP_XOR1>(ar0); ar0 = dpp_add<DPP_XOR2>(ar0); ar0 = dpp_add<DPP_MIR7>(ar0);
            az0 = dpp_add<DPP_XOR1>(az0); az0 = dpp_add<DPP_XOR2>(az0); az0 = dpp_add<DPP_MIR7>(az0);
            an0 = dpp_add<DPP_XOR1>(an0); an0 = dpp_add<DPP_XOR2>(an0); an0 = dpp_add<DPP_MIR7>(an0);
            ar1 = dpp_add<DPP_XOR1>(ar1); ar1 = dpp_add<DPP_XOR2>(ar1); ar1 = dpp_add<DPP_MIR7>(ar1);
            az1 = dpp_add<DPP_XOR1>(az1); az1 = dpp_add<DPP_XOR2>(az1); az1 = dpp_add<DPP_MIR7>(az1);
            an1 = dpp_add<DPP_XOR1>(an1); an1 = dpp_add<DPP_XOR2>(an1); an1 = dpp_add<DPP_MIR7>(an1);

            float ar = uhf ? ar1 : ar0;
            float az = uhf ? az1 : az0;
            float an = uhf ? an1 : an0;

            float sr = xgv.x + ar + bhr;
            float sz = xgv.y + az + bhz;
            float rg = 1.f / (1.f + __expf(-sr));
            float zg = 1.f / (1.f + __expf(-sz));
            float tv = fmaf(rg, an + bhn, xgv.z);
            tv = fminf(fmaxf(tv, -15.f), 15.f);
            float e2 = __expf(-2.f * tv);
            float ng = (1.f - e2) / (1.f + e2);
            hprev = fmaf(zg, hprev, (1.f - zg) * ng);
            if ((kq & 3) == 0) houtb[(tl + 1) * HH + u] = hprev;  // kq=0 -> 2i0, kq=4 -> 2i0+1
            xgv = xgn;
            __syncthreads();
        }
    }

    {
        const int s  = tid & 7;
        const int cc = (tid >> 3) & 1;
        const int tl = tid >> 4;
        const float* hr = &houtb[(tl + 1) * HH + s * 16];
        float acc = 0.f;
        #pragma unroll
        for (int m = 0; m < 16; m += 4) {
            float4 hv = *(const float4*)(hr + m);
            int k = s * 16 + m;
            acc = fmaf(hv.x, wps[(k+0)*2 + cc],
                  fmaf(hv.y, wps[(k+1)*2 + cc],
                  fmaf(hv.z, wps[(k+2)*2 + cc],
                  fmaf(hv.w, wps[(k+3)*2 + cc], acc))));
        }
        acc = dpp_add<DPP_XOR1>(acc);
        acc = dpp_add<DPP_XOR2>(acc);
        acc = dpp_add<DPP_SHL4>(acc);
        if (s == 0)
            outb[((TTT / CHUNK - 1) * CHUNK + tl) * 2 + cc] = acc + wps[2 * RHH + cc];
    }
}

extern "C" void kernel_launch(void* const* d_in, const int* in_sizes, int n_in,
                              void* d_out, int out_size, void* d_ws, size_t ws_size,
                              hipStream_t stream)
{
    const float* x      = (const float*)d_in[0];
    const int*   eidx   = (const int*)d_in[1];
    const int*   runner = (const int*)d_in[2];
    const float* W1     = (const float*)d_in[3];
    const float* b1     = (const float*)d_in[4];
    const float* W2     = (const float*)d_in[5];
    const float* b2     = (const float*)d_in[6];
    const float* W_ih   = (const float*)d_in[7];
    const float* W_hh   = (const float*)d_in[8];
    const float* b_ih   = (const float*)d_in[9];
    const float* b_hh   = (const float*)d_in[10];
    const float* Wp     = (const float*)d_in[11];
    const float* bp     = (const float*)d_in[12];
    float* out = (float*)d_out;

    float* xg = (float*)d_ws;                        // 8192*384 floats = 12.6 MB

    gcn_front<<<GG, 256, 0, stream>>>(x, eidx, runner, W1, b1, W2, b2,
                                      W_ih, b_ih, xg);
    gru_kernel<<<BBB, 512, 0, stream>>>(xg, W_hh, b_hh, Wp, bp, out);
}

// Round 9
// 250.682 us; speedup vs baseline: 1.5027x; 1.5027x over previous
//
#include <hip/hip_runtime.h>
#include <hip/hip_bf16.h>
#include <math.h>

#define GG 8192      // graphs = B*T
#define NODESN 23
#define KK 8
#define DIN 16
#define HH 128
#define RHH 128
#define EPG (NODESN*KK)   // 184 edges per graph
#define TTT 128
#define BBB 64

// ---------------------------------------------------------------------------
// DPP cross-lane add (VALU pipe -- NOT the DS pipe, unlike __shfl_xor).
// ---------------------------------------------------------------------------
template<int CTRL>
static __device__ __forceinline__ float dpp_add(float v) {
    int x = __builtin_amdgcn_update_dpp(0, __float_as_int(v), CTRL, 0xF, 0xF, true);
    return v + __int_as_float(x);
}
#define DPP_XOR1 0xB1   // quad_perm [1,0,3,2]
#define DPP_XOR2 0x4E   // quad_perm [2,3,0,1]
#define DPP_MIR7 0x141  // row_half_mirror: lane l <-> l^7 within 8-lane half-row
#define DPP_SHL4 0x104  // row_shl:4 (lane l <- lane l+4)

#define PIN4(v4) asm volatile("" : "+v"((v4).x), "+v"((v4).y), "+v"((v4).z), "+v"((v4).w))

// ---------------------------------------------------------------------------
// Kernel 1 (R16): GCN layer-1 + aggregation + layer-2 row (R14 structure).
// R15 lesson: phase-4 (xg) fusion is fundamentally wrong (row-major W_ih
// reads = 64 lines/wave-load; per-graph GEMV re-reads W_ih 8192x = 1.6 GB L2
// vs xg_kernel's 8-row tiling at 200 MB).  xg stays a separate kernel.
//
// R16 change vs R14: the 2-hop edge traversal (r -> slot nodes -> sources)
// is HOISTED to kernel entry and fully unrolled.  In R14 it ran inside the
// phase-2 loop: 4-5 sequential 3-deep scalar-load chains (~600 cyc each,
// serialized).  Hoisted + unrolled, all slot chains issue in parallel and
// their latency hides under phase 1's FMA work; phase 2 becomes pure LDS
// gathers.  Front-end is latency-bound (R15: VALUBusy 14.5%, occ 76%), so
// removing serial latency is the right lever.
// ---------------------------------------------------------------------------
__global__ __launch_bounds__(256) void gcn_seq(
    const float* __restrict__ x, const int* __restrict__ esrc,
    const int* __restrict__ runner,
    const float* __restrict__ W1, const float* __restrict__ b1,
    const float* __restrict__ W2, const float* __restrict__ b2,
    float* __restrict__ seq)
{
    __shared__ float t1[NODESN * HH];   // 11776 B
    __shared__ float red[256];          //  1024 B
    __shared__ float hs[HH];            //   512 B

    const int g   = blockIdx.x;
    const int tid = threadIdx.x;
    const int j   = tid & 127;
    // wave-uniform half index (provably uniform -> scalarized loads)
    const int nhu = __builtin_amdgcn_readfirstlane(tid >> 7);

    // ---- hoisted 2-hop edge chain (scalar; overlaps phase 1 below).
    // Half nhu handles slots {nhu, nhu+2, ...} (5 slots for half 0, 4 for 1).
    const int* eg = esrc + (size_t)g * EPG;
    const int gb = g * NODESN;
    const int r  = runner[g];
    int nodes[5];
    int src2[5][KK];
    #pragma unroll
    for (int s5 = 0; s5 < 5; s5++) {
        const int slot = nhu + 2 * s5;
        if (slot < 9) {
            const int node = (slot < 8) ? (eg[r * KK + slot] - gb) : r;
            nodes[s5] = node;
            #pragma unroll
            for (int k = 0; k < KK; k++) src2[s5][k] = eg[node * KK + k] - gb;
        }
    }

    // ---- W1 column j -> registers
    float w[DIN];
    #pragma unroll
    for (int k = 0; k < DIN; k++) w[k] = W1[k * HH + j];
    const float b1j = b1[j];

    // ---- phase 1: t1 = x @ W1 (pre-bias); x rows scalar (uniform addr)
    const float* xgp = x + (size_t)g * NODESN * DIN;
    const int n0 = nhu ? 12 : 0;
    const int n1 = nhu ? NODESN : 12;
    for (int n = n0; n < n1; n++) {
        const float4* xr = (const float4*)(xgp + n * DIN);
        float4 a0 = xr[0], a1 = xr[1], a2 = xr[2], a3 = xr[3];
        float acc;
        acc = fmaf(a0.x, w[0],  fmaf(a0.y, w[1],  fmaf(a0.z, w[2],  fmaf(a0.w, w[3],
              fmaf(a1.x, w[4],  fmaf(a1.y, w[5],  fmaf(a1.z, w[6],  fmaf(a1.w, w[7],
              fmaf(a2.x, w[8],  fmaf(a2.y, w[9],  fmaf(a2.z, w[10], fmaf(a2.w, w[11],
              fmaf(a3.x, w[12], fmaf(a3.y, w[13], fmaf(a3.z, w[14], fmaf(a3.w, w[15],
              0.f))))))))))))))));
        t1[n * HH + j] = acc;
    }
    __syncthreads();

    // ---- phase 2: aggregation -- pure LDS gathers (indices pre-resolved)
    float part = 0.f;
    #pragma unroll
    for (int s5 = 0; s5 < 5; s5++) {
        const int slot = nhu + 2 * s5;
        if (slot < 9) {
            float acc = t1[nodes[s5] * HH + j];
            #pragma unroll
            for (int k = 0; k < KK; k++) acc += t1[src2[s5][k] * HH + j];
            part += fmaxf(acc * (1.f / 9.f) + b1j, 0.f);
        }
    }
    red[tid] = part;
    __syncthreads();
    if (tid < HH) hs[tid] = red[tid] + red[tid + 128];
    __syncthreads();

    // ---- phase 3: seq row = relu((hs @ W2) / 9 + b2)
    {
        const int k0 = nhu * 64;
        float acc = 0.f;
        #pragma unroll 4
        for (int kk = 0; kk < 64; kk += 4) {
            int k = k0 + kk;
            float4 hv = *(const float4*)&hs[k];
            acc = fmaf(hv.x, W2[(k + 0) * HH + j],
                  fmaf(hv.y, W2[(k + 1) * HH + j],
                  fmaf(hv.z, W2[(k + 2) * HH + j],
                  fmaf(hv.w, W2[(k + 3) * HH + j], acc))));
        }
        red[tid] = acc;
        __syncthreads();
        if (tid < HH)
            seq[(size_t)g * HH + tid] =
                fmaxf((red[tid] + red[tid + 128]) * (1.f / 9.f) + b2[tid], 0.f);
    }
}

// ---------------------------------------------------------------------------
// Kernel 3: transpose W_ih [384,128] -> WT [128,384]  (coalescing for xg)
// ---------------------------------------------------------------------------
__global__ void transpose_wih(const float* __restrict__ W, float* __restrict__ WT)
{
    int idx = blockIdx.x * 256 + threadIdx.x;
    if (idx < 3 * RHH * RHH) {
        int jj = idx / RHH, kk = idx - jj * RHH;
        WT[kk * (3 * RHH) + jj] = W[idx];
    }
}

// ---------------------------------------------------------------------------
// Kernel 4: xg = seq @ W_ih^T + b_ih   [8192,128]@[128,384]
// 8-row tiles: W_ih/WT read once per 8 graphs (200 MB L2 total, coalesced).
// ---------------------------------------------------------------------------
__global__ __launch_bounds__(384) void xg_kernel(
    const float* __restrict__ seq, const float* __restrict__ WT,
    const float* __restrict__ b_ih, float* __restrict__ xg)
{
    const int tid = threadIdx.x;
    const int m0 = blockIdx.x * 8;
    const float* srow = seq + (size_t)m0 * RHH;
    float acc[8];
    const float bv = b_ih[tid];
    #pragma unroll
    for (int mi = 0; mi < 8; mi++) acc[mi] = bv;
    for (int k = 0; k < RHH; k += 4) {
        float w0 = WT[(k+0)*384 + tid];
        float w1 = WT[(k+1)*384 + tid];
        float w2 = WT[(k+2)*384 + tid];
        float w3 = WT[(k+3)*384 + tid];
        #pragma unroll
        for (int mi = 0; mi < 8; mi++) {
            float4 sv = *(const float4*)(srow + mi * RHH + k);
            acc[mi] = fmaf(sv.x, w0, fmaf(sv.y, w1, fmaf(sv.z, w2, fmaf(sv.w, w3, acc[mi]))));
        }
    }
    #pragma unroll
    for (int mi = 0; mi < 8; mi++)
        xg[(size_t)(m0 + mi) * 384 + tid] = acc[mi];
}

// ---------------------------------------------------------------------------
// Kernel 5: GRU (byte-identical to R13/R14: 512 thr, ~99 us -- control).
// ---------------------------------------------------------------------------
#define CHUNK 32
#define XGB_FLOATS (CHUNK * HH * 4)      // 16384 floats = 64 KB

__global__ __launch_bounds__(512)
__attribute__((amdgpu_waves_per_eu(2, 2)))
void gru_kernel(
    const float* __restrict__ xg, const float* __restrict__ W_hh,
    const float* __restrict__ b_hh, const float* __restrict__ Wp,
    const float* __restrict__ bp, float* __restrict__ out)
{
    __shared__ float xgbuf[XGB_FLOATS];          // [tl][i][{xr,xz,xn,pad}]
    __shared__ float houtb[(CHUNK + 2) * HH];    // rows 1..32 = h(t); row 32 also carry
    __shared__ float wps[2 * RHH + 2];           // Wp + bp

    const int b   = blockIdx.x;
    const int tid = threadIdx.x;
    const int kq  = tid & 7;       // k-eighth, lane bits 0-2 (DPP butterfly domain)
    const int i0  = tid >> 3;      // unit pair 0..63
    const int uhf = kq >> 2;       // which unit of the pair this lane's gates handle
    const int u   = 2 * i0 + uhf;  // this lane's gate unit

    float4 wr0[4], wz0[4], wn0[4], wr1[4], wz1[4], wn1[4];
    int hof[4];
    {
        const float* w0 = W_hh + (size_t)(2 * i0) * RHH + kq * 16;
        #pragma unroll
        for (int m = 0; m < 4; m++) {
            const int off = 4 * ((m + kq) & 3);
            hof[m] = kq * 16 + off;
            wr0[m] = *(const float4*)(w0 + off);
            wz0[m] = *(const float4*)(w0 + RHH * RHH + off);
            wn0[m] = *(const float4*)(w0 + 2 * RHH * RHH + off);
            wr1[m] = *(const float4*)(w0 + RHH + off);
            wz1[m] = *(const float4*)(w0 + RHH * RHH + RHH + off);
            wn1[m] = *(const float4*)(w0 + 2 * RHH * RHH + RHH + off);
        }
    }
    #pragma unroll
    for (int m = 0; m < 4; m++) {
        PIN4(wr0[m]); PIN4(wz0[m]); PIN4(wn0[m]);
        PIN4(wr1[m]); PIN4(wz1[m]); PIN4(wn1[m]);
    }
    const float bhr = b_hh[u];
    const float bhz = b_hh[RHH + u];
    const float bhn = b_hh[2 * RHH + u];

    if (tid < 2 * RHH) wps[tid] = Wp[tid];
    if (tid < 2)       wps[2 * RHH + tid] = bp[tid];
    if (tid < HH)      houtb[CHUNK * HH + tid] = 0.f;   // carry row = h(-1) = 0
    float hprev = 0.f;

    const float* xbase = xg + (size_t)b * TTT * 3 * RHH;
    float* outb = out + (size_t)b * TTT * 2;

    for (int c = 0; c < TTT / CHUNK; c++) {
        #pragma unroll
        for (int k2 = 0; k2 < 8; k2++) {
            int slot = tid + (k2 << 9);          // 0..4095
            int tl = slot >> 7, ii = slot & 127;
            const float* gsrc = xbase + (size_t)(c * CHUNK + tl) * 384 + ii;
            float4 v;
            v.x = gsrc[0]; v.y = gsrc[128]; v.z = gsrc[256]; v.w = 0.f;
            *(float4*)&xgbuf[slot << 2] = v;
        }
        if (c > 0) {
            const int s  = tid & 7;              // 16-float k-slice
            const int cc = (tid >> 3) & 1;
            const int tl = tid >> 4;             // 0..31
            const float* hr = &houtb[(tl + 1) * HH + s * 16];
            float acc = 0.f;
            #pragma unroll
            for (int m = 0; m < 16; m += 4) {
                float4 hv = *(const float4*)(hr + m);
                int k = s * 16 + m;
                acc = fmaf(hv.x, wps[(k+0)*2 + cc],
                      fmaf(hv.y, wps[(k+1)*2 + cc],
                      fmaf(hv.z, wps[(k+2)*2 + cc],
                      fmaf(hv.w, wps[(k+3)*2 + cc], acc))));
            }
            acc = dpp_add<DPP_XOR1>(acc);
            acc = dpp_add<DPP_XOR2>(acc);
            acc = dpp_add<DPP_SHL4>(acc);        // valid in lanes s<4
            if (s == 0)
                outb[((c - 1) * CHUNK + tl) * 2 + cc] = acc + wps[2 * RHH + cc];
        }
        __syncthreads();

        float4 xgv = *(const float4*)&xgbuf[u << 2];   // tl=0 row
        for (int tl = 0; tl < CHUNK; tl++) {
            const float* hrow = &houtb[(tl == 0 ? CHUNK : tl) * HH];
            float4 xgn = xgv;
            if (tl + 1 < CHUNK)
                xgn = *(const float4*)&xgbuf[((tl + 1) * HH + u) << 2];

            float ar0 = 0.f, az0 = 0.f, an0 = 0.f;
            float ar1 = 0.f, az1 = 0.f, an1 = 0.f;
            #pragma unroll
            for (int m = 0; m < 4; m++) {
                float4 hv = *(const float4*)(hrow + hof[m]);
                ar0 = fmaf(hv.x, wr0[m].x, fmaf(hv.y, wr0[m].y, fmaf(hv.z, wr0[m].z, fmaf(hv.w, wr0[m].w, ar0))));
                az0 = fmaf(hv.x, wz0[m].x, fmaf(hv.y, wz0[m].y, fmaf(hv.z, wz0[m].z, fmaf(hv.w, wz0[m].w, az0))));
                an0 = fmaf(hv.x, wn0[m].x, fmaf(hv.y, wn0[m].y, fmaf(hv.z, wn0[m].z, fmaf(hv.w, wn0[m].w, an0))));
                ar1 = fmaf(hv.x, wr1[m].x, fmaf(hv.y, wr1[m].y, fmaf(hv.z, wr1[m].z, fmaf(hv.w, wr1[m].w, ar1))));
                az1 = fmaf(hv.x, wz1[m].x, fmaf(hv.y, wz1[m].y, fmaf(hv.z, wz1[m].z, fmaf(hv.w, wz1[m].w, az1))));
                an1 = fmaf(hv.x, wn1[m].x, fmaf(hv.y, wn1[m].y, fmaf(hv.z, wn1[m].z, fmaf(hv.w, wn1[m].w, an1))));
            }
            ar0 = dpp_add<DPP_XOR1>(ar0); ar0 = dpp_add<DPP_XOR2>(ar0); ar0 = dpp_add<DPP_MIR7>(ar0);
            az0 = dpp_add<DPP_XOR1>(az0); az0 = dpp_add<DPP_XOR2>(az0); az0 = dpp_add<DPP_MIR7>(az0);
            an0 = dpp_add<DPP_XOR1>(an0); an0 = dpp_add<DPP_XOR2>(an0); an0 = dpp_add<DPP_MIR7>(an0);
            ar1 = dpp_add<DPP_XOR1>(ar1); ar1 = dpp_add<DPP_XOR2>(ar1); ar1 = dpp_add<DPP_MIR7>(ar1);
            az1 = dpp_add<DPP_XOR1>(az1); az1 = dpp_add<DPP_XOR2>(az1); az1 = dpp_add<DPP_MIR7>(az1);
            an1 = dpp_add<DPP_XOR1>(an1); an1 = dpp_add<DPP_XOR2>(an1); an1 = dpp_add<DPP_MIR7>(an1);

            float ar = uhf ? ar1 : ar0;
            float az = uhf ? az1 : az0;
            float an = uhf ? an1 : an0;

            float sr = xgv.x + ar + bhr;
            float sz = xgv.y + az + bhz;
            float rg = 1.f / (1.f + __expf(-sr));
            float zg = 1.f / (1.f + __expf(-sz));
            float tv = fmaf(rg, an + bhn, xgv.z);
            tv = fminf(fmaxf(tv, -15.f), 15.f);
            float e2 = __expf(-2.f * tv);
            float ng = (1.f - e2) / (1.f + e2);
            hprev = fmaf(zg, hprev, (1.f - zg) * ng);
            if ((kq & 3) == 0) houtb[(tl + 1) * HH + u] = hprev;  // kq=0 -> 2i0, kq=4 -> 2i0+1
            xgv = xgn;
            __syncthreads();
        }
    }

    {
        const int s  = tid & 7;
        const int cc = (tid >> 3) & 1;
        const int tl = tid >> 4;
        const float* hr = &houtb[(tl + 1) * HH + s * 16];
        float acc = 0.f;
        #pragma unroll
        for (int m = 0; m < 16; m += 4) {
            float4 hv = *(const float4*)(hr + m);
            int k = s * 16 + m;
            acc = fmaf(hv.x, wps[(k+0)*2 + cc],
                  fmaf(hv.y, wps[(k+1)*2 + cc],
                  fmaf(hv.z, wps[(k+2)*2 + cc],
                  fmaf(hv.w, wps[(k+3)*2 + cc], acc))));
        }
        acc = dpp_add<DPP_XOR1>(acc);
        acc = dpp_add<DPP_XOR2>(acc);
        acc = dpp_add<DPP_SHL4>(acc);
        if (s == 0)
            outb[((TTT / CHUNK - 1) * CHUNK + tl) * 2 + cc] = acc + wps[2 * RHH + cc];
    }
}

extern "C" void kernel_launch(void* const* d_in, const int* in_sizes, int n_in,
                              void* d_out, int out_size, void* d_ws, size_t ws_size,
                              hipStream_t stream)
{
    const float* x      = (const float*)d_in[0];
    const int*   eidx   = (const int*)d_in[1];
    const int*   runner = (const int*)d_in[2];
    const float* W1     = (const float*)d_in[3];
    const float* b1     = (const float*)d_in[4];
    const float* W2     = (const float*)d_in[5];
    const float* b2     = (const float*)d_in[6];
    const float* W_ih   = (const float*)d_in[7];
    const float* W_hh   = (const float*)d_in[8];
    const float* b_ih   = (const float*)d_in[9];
    const float* b_hh   = (const float*)d_in[10];
    const float* Wp     = (const float*)d_in[11];
    const float* bp     = (const float*)d_in[12];
    float* out = (float*)d_out;

    float* seq = (float*)d_ws;                       // 8192*128   [0, 4 MB)
    float* xg  = seq + (size_t)GG * HH;              // 8192*384   [4, 16.6 MB)
    float* WT  = xg + (size_t)GG * 3 * RHH;          // 128*384

    transpose_wih<<<192, 256, 0, stream>>>(W_ih, WT);
    gcn_seq<<<GG, 256, 0, stream>>>(x, eidx, runner, W1, b1, W2, b2, seq);
    xg_kernel<<<GG / 8, 384, 0, stream>>>(seq, WT, b_ih, xg);
    gru_kernel<<<BBB, 512, 0, stream>>>(xg, W_hh, b_hh, Wp, bp, out);
}

// Round 10
// 242.948 us; speedup vs baseline: 1.5506x; 1.0318x over previous
//
#include <hip/hip_runtime.h>
#include <hip/hip_bf16.h>
#include <math.h>

#define GG 8192      // graphs = B*T
#define NODESN 23
#define KK 8
#define DIN 16
#define HH 128
#define RHH 128
#define EPG (NODESN*KK)   // 184 edges per graph
#define TTT 128
#define BBB 64

// ---------------------------------------------------------------------------
// DPP cross-lane add (VALU pipe -- NOT the DS pipe, unlike __shfl_xor).
// ---------------------------------------------------------------------------
template<int CTRL>
static __device__ __forceinline__ float dpp_add(float v) {
    int x = __builtin_amdgcn_update_dpp(0, __float_as_int(v), CTRL, 0xF, 0xF, true);
    return v + __int_as_float(x);
}
#define DPP_XOR1 0xB1   // quad_perm [1,0,3,2]
#define DPP_XOR2 0x4E   // quad_perm [2,3,0,1]
#define DPP_MIR7 0x141  // row_half_mirror: lane l <-> l^7 within 8-lane half-row
#define DPP_SHL4 0x104  // row_shl:4 (lane l <- lane l+4)

#define PIN4(v4) asm volatile("" : "+v"((v4).x), "+v"((v4).y), "+v"((v4).z), "+v"((v4).w))

// ---------------------------------------------------------------------------
// Kernel 1: GCN layer-1 + aggregation + fused layer-2 row (exact R14 version;
// R16's hoisted edge chain cost ~8 us and is reverted).
// ---------------------------------------------------------------------------
__global__ __launch_bounds__(256) void gcn_seq(
    const float* __restrict__ x, const int* __restrict__ esrc,
    const int* __restrict__ runner,
    const float* __restrict__ W1, const float* __restrict__ b1,
    const float* __restrict__ W2, const float* __restrict__ b2,
    float* __restrict__ seq)
{
    __shared__ float t1[NODESN * HH];   // 11776 B
    __shared__ float red[256];          //  1024 B
    __shared__ float hs[HH];            //   512 B

    const int g   = blockIdx.x;
    const int tid = threadIdx.x;
    const int j   = tid & 127;
    const int nhu = __builtin_amdgcn_readfirstlane(tid >> 7);

    // ---- W1 column j -> registers
    float w[DIN];
    #pragma unroll
    for (int k = 0; k < DIN; k++) w[k] = W1[k * HH + j];
    const float b1j = b1[j];

    // ---- phase 1: t1 = x @ W1 (pre-bias); x rows scalar (uniform addr)
    const float* xgp = x + (size_t)g * NODESN * DIN;
    const int n0 = nhu ? 12 : 0;
    const int n1 = nhu ? NODESN : 12;
    for (int n = n0; n < n1; n++) {
        const float4* xr = (const float4*)(xgp + n * DIN);
        float4 a0 = xr[0], a1 = xr[1], a2 = xr[2], a3 = xr[3];
        float acc;
        acc = fmaf(a0.x, w[0],  fmaf(a0.y, w[1],  fmaf(a0.z, w[2],  fmaf(a0.w, w[3],
              fmaf(a1.x, w[4],  fmaf(a1.y, w[5],  fmaf(a1.z, w[6],  fmaf(a1.w, w[7],
              fmaf(a2.x, w[8],  fmaf(a2.y, w[9],  fmaf(a2.z, w[10], fmaf(a2.w, w[11],
              fmaf(a3.x, w[12], fmaf(a3.y, w[13], fmaf(a3.z, w[14], fmaf(a3.w, w[15],
              0.f))))))))))))))));
        t1[n * HH + j] = acc;
    }
    __syncthreads();

    // ---- phase 2: runner-neighborhood aggregation (edge indices scalar)
    const int* eg = esrc + (size_t)g * EPG;
    const int gb = g * NODESN;
    const int r  = runner[g];
    float part = 0.f;
    for (int slot = nhu; slot < 9; slot += 2) {
        int node = (slot < 8) ? (eg[r * KK + slot] - gb) : r;
        float acc = t1[node * HH + j];
        #pragma unroll
        for (int k = 0; k < KK; k++) acc += t1[(eg[node * KK + k] - gb) * HH + j];
        part += fmaxf(acc * (1.f / 9.f) + b1j, 0.f);
    }
    red[tid] = part;
    __syncthreads();
    if (tid < HH) hs[tid] = red[tid] + red[tid + 128];
    __syncthreads();

    // ---- phase 3: seq row = relu((hs @ W2) / 9 + b2)
    {
        const int k0 = nhu * 64;
        float acc = 0.f;
        #pragma unroll 4
        for (int kk = 0; kk < 64; kk += 4) {
            int k = k0 + kk;
            float4 hv = *(const float4*)&hs[k];
            acc = fmaf(hv.x, W2[(k + 0) * HH + j],
                  fmaf(hv.y, W2[(k + 1) * HH + j],
                  fmaf(hv.z, W2[(k + 2) * HH + j],
                  fmaf(hv.w, W2[(k + 3) * HH + j], acc))));
        }
        red[tid] = acc;
        __syncthreads();
        if (tid < HH)
            seq[(size_t)g * HH + tid] =
                fmaxf((red[tid] + red[tid + 128]) * (1.f / 9.f) + b2[tid], 0.f);
    }
}

// ---------------------------------------------------------------------------
// Kernel 3: transpose W_ih [384,128] -> WT [128,384]  (coalescing for xg)
// ---------------------------------------------------------------------------
__global__ void transpose_wih(const float* __restrict__ W, float* __restrict__ WT)
{
    int idx = blockIdx.x * 256 + threadIdx.x;
    if (idx < 3 * RHH * RHH) {
        int jj = idx / RHH, kk = idx - jj * RHH;
        WT[kk * (3 * RHH) + jj] = W[idx];
    }
}

// ---------------------------------------------------------------------------
// Kernel 4: xg = seq @ W_ih^T + b_ih   [8192,128]@[128,384]
// ---------------------------------------------------------------------------
__global__ __launch_bounds__(384) void xg_kernel(
    const float* __restrict__ seq, const float* __restrict__ WT,
    const float* __restrict__ b_ih, float* __restrict__ xg)
{
    const int tid = threadIdx.x;
    const int m0 = blockIdx.x * 8;
    const float* srow = seq + (size_t)m0 * RHH;
    float acc[8];
    const float bv = b_ih[tid];
    #pragma unroll
    for (int mi = 0; mi < 8; mi++) acc[mi] = bv;
    for (int k = 0; k < RHH; k += 4) {
        float w0 = WT[(k+0)*384 + tid];
        float w1 = WT[(k+1)*384 + tid];
        float w2 = WT[(k+2)*384 + tid];
        float w3 = WT[(k+3)*384 + tid];
        #pragma unroll
        for (int mi = 0; mi < 8; mi++) {
            float4 sv = *(const float4*)(srow + mi * RHH + k);
            acc[mi] = fmaf(sv.x, w0, fmaf(sv.y, w1, fmaf(sv.z, w2, fmaf(sv.w, w3, acc[mi]))));
        }
    }
    #pragma unroll
    for (int mi = 0; mi < 8; mi++)
        xg[(size_t)(m0 + mi) * 384 + tid] = acc[mi];
}

// ---------------------------------------------------------------------------
// Kernel 5: GRU -- R17: identical to R13/R14 EXCEPT __launch_bounds__(512, 2).
//
// The 2nd launch_bounds arg = MIN WAVES PER EU (guide §1).  Previous rounds
// used bare __launch_bounds__(512) + amdgpu_waves_per_eu(2,2); the allocator
// ignored the attribute and targeted its own occupancy (~5-8 waves/EU ->
// 88/56 VGPRs), refusing to keep the 96 weight floats resident (AGPR/L2
// shuttle = the measured 2.5x phantom VALU issue).  (512, 2) sets the
// allocation budget to 256 VGPR/thread through the channel the backend
// actually honors.  Occupancy is unchanged either way: 84 KB LDS already
// limits to 1 block/CU = 2 waves/EU.
// ---------------------------------------------------------------------------
#define CHUNK 32
#define XGB_FLOATS (CHUNK * HH * 4)      // 16384 floats = 64 KB

__global__ __launch_bounds__(512, 2)
void gru_kernel(
    const float* __restrict__ xg, const float* __restrict__ W_hh,
    const float* __restrict__ b_hh, const float* __restrict__ Wp,
    const float* __restrict__ bp, float* __restrict__ out)
{
    __shared__ float xgbuf[XGB_FLOATS];          // [tl][i][{xr,xz,xn,pad}]
    __shared__ float houtb[(CHUNK + 2) * HH];    // rows 1..32 = h(t); row 32 also carry
    __shared__ float wps[2 * RHH + 2];           // Wp + bp

    const int b   = blockIdx.x;
    const int tid = threadIdx.x;
    const int kq  = tid & 7;       // k-eighth, lane bits 0-2 (DPP butterfly domain)
    const int i0  = tid >> 3;      // unit pair 0..63
    const int uhf = kq >> 2;       // which unit of the pair this lane's gates handle
    const int u   = 2 * i0 + uhf;  // this lane's gate unit

    float4 wr0[4], wz0[4], wn0[4], wr1[4], wz1[4], wn1[4];
    int hof[4];
    {
        const float* w0 = W_hh + (size_t)(2 * i0) * RHH + kq * 16;
        #pragma unroll
        for (int m = 0; m < 4; m++) {
            const int off = 4 * ((m + kq) & 3);
            hof[m] = kq * 16 + off;
            wr0[m] = *(const float4*)(w0 + off);
            wz0[m] = *(const float4*)(w0 + RHH * RHH + off);
            wn0[m] = *(const float4*)(w0 + 2 * RHH * RHH + off);
            wr1[m] = *(const float4*)(w0 + RHH + off);
            wz1[m] = *(const float4*)(w0 + RHH * RHH + RHH + off);
            wn1[m] = *(const float4*)(w0 + 2 * RHH * RHH + RHH + off);
        }
    }
    #pragma unroll
    for (int m = 0; m < 4; m++) {
        PIN4(wr0[m]); PIN4(wz0[m]); PIN4(wn0[m]);
        PIN4(wr1[m]); PIN4(wz1[m]); PIN4(wn1[m]);
    }
    const float bhr = b_hh[u];
    const float bhz = b_hh[RHH + u];
    const float bhn = b_hh[2 * RHH + u];

    if (tid < 2 * RHH) wps[tid] = Wp[tid];
    if (tid < 2)       wps[2 * RHH + tid] = bp[tid];
    if (tid < HH)      houtb[CHUNK * HH + tid] = 0.f;   // carry row = h(-1) = 0
    float hprev = 0.f;

    const float* xbase = xg + (size_t)b * TTT * 3 * RHH;
    float* outb = out + (size_t)b * TTT * 2;

    for (int c = 0; c < TTT / CHUNK; c++) {
        #pragma unroll
        for (int k2 = 0; k2 < 8; k2++) {
            int slot = tid + (k2 << 9);          // 0..4095
            int tl = slot >> 7, ii = slot & 127;
            const float* gsrc = xbase + (size_t)(c * CHUNK + tl) * 384 + ii;
            float4 v;
            v.x = gsrc[0]; v.y = gsrc[128]; v.z = gsrc[256]; v.w = 0.f;
            *(float4*)&xgbuf[slot << 2] = v;
        }
        if (c > 0) {
            const int s  = tid & 7;              // 16-float k-slice
            const int cc = (tid >> 3) & 1;
            const int tl = tid >> 4;             // 0..31
            const float* hr = &houtb[(tl + 1) * HH + s * 16];
            float acc = 0.f;
            #pragma unroll
            for (int m = 0; m < 16; m += 4) {
                float4 hv = *(const float4*)(hr + m);
                int k = s * 16 + m;
                acc = fmaf(hv.x, wps[(k+0)*2 + cc],
                      fmaf(hv.y, wps[(k+1)*2 + cc],
                      fmaf(hv.z, wps[(k+2)*2 + cc],
                      fmaf(hv.w, wps[(k+3)*2 + cc], acc))));
            }
            acc = dpp_add<DPP_XOR1>(acc);
            acc = dpp_add<DPP_XOR2>(acc);
            acc = dpp_add<DPP_SHL4>(acc);        // valid in lanes s<4
            if (s == 0)
                outb[((c - 1) * CHUNK + tl) * 2 + cc] = acc + wps[2 * RHH + cc];
        }
        __syncthreads();

        float4 xgv = *(const float4*)&xgbuf[u << 2];   // tl=0 row
        for (int tl = 0; tl < CHUNK; tl++) {
            const float* hrow = &houtb[(tl == 0 ? CHUNK : tl) * HH];
            float4 xgn = xgv;
            if (tl + 1 < CHUNK)
                xgn = *(const float4*)&xgbuf[((tl + 1) * HH + u) << 2];

            float ar0 = 0.f, az0 = 0.f, an0 = 0.f;
            float ar1 = 0.f, az1 = 0.f, an1 = 0.f;
            #pragma unroll
            for (int m = 0; m < 4; m++) {
                float4 hv = *(const float4*)(hrow + hof[m]);
                ar0 = fmaf(hv.x, wr0[m].x, fmaf(hv.y, wr0[m].y, fmaf(hv.z, wr0[m].z, fmaf(hv.w, wr0[m].w, ar0))));
                az0 = fmaf(hv.x, wz0[m].x, fmaf(hv.y, wz0[m].y, fmaf(hv.z, wz0[m].z, fmaf(hv.w, wz0[m].w, az0))));
                an0 = fmaf(hv.x, wn0[m].x, fmaf(hv.y, wn0[m].y, fmaf(hv.z, wn0[m].z, fmaf(hv.w, wn0[m].w, an0))));
                ar1 = fmaf(hv.x, wr1[m].x, fmaf(hv.y, wr1[m].y, fmaf(hv.z, wr1[m].z, fmaf(hv.w, wr1[m].w, ar1))));
                az1 = fmaf(hv.x, wz1[m].x, fmaf(hv.y, wz1[m].y, fmaf(hv.z, wz1[m].z, fmaf(hv.w, wz1[m].w, az1))));
                an1 = fmaf(hv.x, wn1[m].x, fmaf(hv.y, wn1[m].y, fmaf(hv.z, wn1[m].z, fmaf(hv.w, wn1[m].w, an1))));
            }
            ar0 = dpp_add<DPP_XOR1>(ar0); ar0 = dpp_add<DPP_XOR2>(ar0); ar0 = dpp_add<DPP_MIR7>(ar0);
            az0 = dpp_add<DPP_XOR1>(az0); az0 = dpp_add<DPP_XOR2>(az0); az0 = dpp_add<DPP_MIR7>(az0);
            an0 = dpp_add<DPP_XOR1>(an0); an0 = dpp_add<DPP_XOR2>(an0); an0 = dpp_add<DPP_MIR7>(an0);
            ar1 = dpp_add<DPP_XOR1>(ar1); ar1 = dpp_add<DPP_XOR2>(ar1); ar1 = dpp_add<DPP_MIR7>(ar1);
            az1 = dpp_add<DPP_XOR1>(az1); az1 = dpp_add<DPP_XOR2>(az1); az1 = dpp_add<DPP_MIR7>(az1);
            an1 = dpp_add<DPP_XOR1>(an1); an1 = dpp_add<DPP_XOR2>(an1); an1 = dpp_add<DPP_MIR7>(an1);

            float ar = uhf ? ar1 : ar0;
            float az = uhf ? az1 : az0;
            float an = uhf ? an1 : an0;

            float sr = xgv.x + ar + bhr;
            float sz = xgv.y + az + bhz;
            float rg = 1.f / (1.f + __expf(-sr));
            float zg = 1.f / (1.f + __expf(-sz));
            float tv = fmaf(rg, an + bhn, xgv.z);
            tv = fminf(fmaxf(tv, -15.f), 15.f);
            float e2 = __expf(-2.f * tv);
            float ng = (1.f - e2) / (1.f + e2);
            hprev = fmaf(zg, hprev, (1.f - zg) * ng);
            if ((kq & 3) == 0) houtb[(tl + 1) * HH + u] = hprev;  // kq=0 -> 2i0, kq=4 -> 2i0+1
            xgv = xgn;
            __syncthreads();
        }
    }

    {
        const int s  = tid & 7;
        const int cc = (tid >> 3) & 1;
        const int tl = tid >> 4;
        const float* hr = &houtb[(tl + 1) * HH + s * 16];
        float acc = 0.f;
        #pragma unroll
        for (int m = 0; m < 16; m += 4) {
            float4 hv = *(const float4*)(hr + m);
            int k = s * 16 + m;
            acc = fmaf(hv.x, wps[(k+0)*2 + cc],
                  fmaf(hv.y, wps[(k+1)*2 + cc],
                  fmaf(hv.z, wps[(k+2)*2 + cc],
                  fmaf(hv.w, wps[(k+3)*2 + cc], acc))));
        }
        acc = dpp_add<DPP_XOR1>(acc);
        acc = dpp_add<DPP_XOR2>(acc);
        acc = dpp_add<DPP_SHL4>(acc);
        if (s == 0)
            outb[((TTT / CHUNK - 1) * CHUNK + tl) * 2 + cc] = acc + wps[2 * RHH + cc];
    }
}

extern "C" void kernel_launch(void* const* d_in, const int* in_sizes, int n_in,
                              void* d_out, int out_size, void* d_ws, size_t ws_size,
                              hipStream_t stream)
{
    const float* x      = (const float*)d_in[0];
    const int*   eidx   = (const int*)d_in[1];
    const int*   runner = (const int*)d_in[2];
    const float* W1     = (const float*)d_in[3];
    const float* b1     = (const float*)d_in[4];
    const float* W2     = (const float*)d_in[5];
    const float* b2     = (const float*)d_in[6];
    const float* W_ih   = (const float*)d_in[7];
    const float* W_hh   = (const float*)d_in[8];
    const float* b_ih   = (const float*)d_in[9];
    const float* b_hh   = (const float*)d_in[10];
    const float* Wp     = (const float*)d_in[11];
    const float* bp     = (const float*)d_in[12];
    float* out = (float*)d_out;

    float* seq = (float*)d_ws;                       // 8192*128   [0, 4 MB)
    float* xg  = seq + (size_t)GG * HH;              // 8192*384   [4, 16.6 MB)
    float* WT  = xg + (size_t)GG * 3 * RHH;          // 128*384

    transpose_wih<<<192, 256, 0, stream>>>(W_ih, WT);
    gcn_seq<<<GG, 256, 0, stream>>>(x, eidx, runner, W1, b1, W2, b2, seq);
    xg_kernel<<<GG / 8, 384, 0, stream>>>(seq, WT, b_ih, xg);
    gru_kernel<<<BBB, 512, 0, stream>>>(xg, W_hh, b_hh, Wp, bp, out);
}